// Round 8
// baseline (622.097 us; speedup 1.0000x reference)
//
#include <hip/hip_runtime.h>

constexpr int H = 128;
constexpr int F = 9;
constexpr float BN_EPS = 1e-5f;
constexpr int NBMAX = 512;      // max dst buckets (256 nodes each, N <= 131072)
constexpr int MLPB = 256;       // mlp grid size (fixed: partials slots)

typedef _Float16 f16x8 __attribute__((ext_vector_type(8)));
typedef _Float16 f16x4 __attribute__((ext_vector_type(4)));
typedef float    f32x4 __attribute__((ext_vector_type(4)));

// ---------------- bucketed CSR build (no per-node global atomics) ----------------

__global__ __launch_bounds__(256) void bucket_count_kernel(
    const int* __restrict__ dst, int* __restrict__ bcnt, int E, int nbuckets) {
    __shared__ int h[NBMAX];
    int t = threadIdx.x;
    for (int i = t; i < nbuckets; i += 256) h[i] = 0;
    __syncthreads();
    for (int i = blockIdx.x * 256 + t; i < E; i += gridDim.x * 256)
        atomicAdd(&h[dst[i] >> 8], 1);
    __syncthreads();
    for (int i = t; i < nbuckets; i += 256) {
        int c = h[i];
        if (c) atomicAdd(&bcnt[i], c);
    }
}

__global__ __launch_bounds__(NBMAX) void bucket_scan_kernel(
    const int* __restrict__ bcnt, int* __restrict__ bbase, int* __restrict__ bcur, int nbuckets) {
    __shared__ int s[NBMAX];
    int t = threadIdx.x;
    int v = (t < nbuckets) ? bcnt[t] : 0;
    s[t] = v;
    __syncthreads();
    for (int off = 1; off < NBMAX; off <<= 1) {
        int tmp = (t >= off) ? s[t - off] : 0;
        __syncthreads();
        s[t] += tmp;
        __syncthreads();
    }
    if (t < nbuckets) {
        int ex = s[t] - v;
        bbase[t] = ex;
        bcur[t] = ex;
    }
}

// Pass B: group edges by bucket; packed entry = src | ((dst&255)<<17)  (src < 2^17)
__global__ __launch_bounds__(256) void bucket_fill_kernel(
    const int* __restrict__ src, const int* __restrict__ dst, int* __restrict__ bcur,
    int* __restrict__ ebuf, int E, int nbuckets, int chunk) {
    __shared__ int h[NBMAX];
    int t = threadIdx.x;
    for (int i = t; i < nbuckets; i += 256) h[i] = 0;
    __syncthreads();
    int lo = blockIdx.x * chunk, hi = min(E, lo + chunk);
    for (int i = lo + t; i < hi; i += 256)
        atomicAdd(&h[dst[i] >> 8], 1);
    __syncthreads();
    for (int i = t; i < nbuckets; i += 256) {
        int c = h[i];
        h[i] = c ? atomicAdd(&bcur[i], c) : 0;   // h becomes block's write cursor
    }
    __syncthreads();
    for (int i = lo + t; i < hi; i += 256) {
        int d = dst[i];
        int p = atomicAdd(&h[d >> 8], 1);        // LDS atomic
        ebuf[p] = src[i] | ((d & 255) << 17);
    }
}

__global__ __launch_bounds__(256) void csr_build_kernel(
    const int* __restrict__ bbase, const int* __restrict__ bcnt,
    const int* __restrict__ ebuf, int* __restrict__ row_start,
    int* __restrict__ col, int N, int E) {
    __shared__ int hist[256];
    __shared__ int sc[256];
    int b = blockIdx.x, t = threadIdx.x;
    int beg = bbase[b], cnt = bcnt[b];
    hist[t] = 0;
    __syncthreads();
    for (int i = t; i < cnt; i += 256)
        atomicAdd(&hist[(ebuf[beg + i] >> 17) & 255], 1);
    __syncthreads();
    int v = hist[t];
    sc[t] = v;
    __syncthreads();
    for (int off = 1; off < 256; off <<= 1) {
        int tmp = (t >= off) ? sc[t - off] : 0;
        __syncthreads();
        sc[t] += tmp;
        __syncthreads();
    }
    int ex = sc[t] - v;                 // exclusive prefix within bucket
    int node = b * 256 + t;
    if (node < N) row_start[node] = beg + ex;
    hist[t] = ex;                       // becomes per-node cursor
    __syncthreads();
    for (int i = t; i < cnt; i += 256) {
        int e = ebuf[beg + i];
        int p = atomicAdd(&hist[(e >> 17) & 255], 1);   // LDS atomic
        col[beg + p] = e & 0x1FFFF;
    }
    if (b == 0 && t == 0) row_start[N] = E;
}

// ---------------- weight prep: f32 (K x 128) -> f16 in MFMA-FRAGMENT order ----------------
// slot 0: w2_0 ; slots 1..4: ws2[0..3] ; slots 5..8: ws1[0..3]
__global__ void prep_w_kernel(const float* __restrict__ w20, const float* __restrict__ ws1,
                              const float* __restrict__ ws2, _Float16* __restrict__ wf) {
    int i = blockIdx.x * blockDim.x + threadIdx.x;
    if (i >= 9 * 16384) return;
    int w = i >> 14, r = i & 16383;
    int tt = r >> 11, ks = (r >> 9) & 3, lane = (r >> 3) & 63, e = r & 7;
    int n = tt * 16 + (lane & 15);
    int k = ks * 32 + (lane >> 4) * 8 + e;
    const float* src = (w == 0) ? w20 : (w <= 4 ? ws2 + (size_t)(w - 1) * 16384
                                                : ws1 + (size_t)(w - 5) * 16384);
    wf[i] = (_Float16)src[k * H + n];
}

// pad x (N x 9 f32) -> xp (N x 16 f32, zero-padded)
__global__ void prep_x_kernel(const float* __restrict__ x, float* __restrict__ xp, int N) {
    int i = blockIdx.x * blockDim.x + threadIdx.x;
    if (i >= N * 16) return;
    int n = i >> 4, c = i & 15;
    xp[i] = (c < F) ? x[n * F + c] : 0.f;
}

// ---------------- layer 0: gather (padded F=16) + fused 9->128 linear + ReLU ----------------
__global__ __launch_bounds__(256) void gather0_kernel(
    const float* __restrict__ xp, const int* __restrict__ row_start,
    const int* __restrict__ col, const float* __restrict__ w1,
    const float* __restrict__ b1, _Float16* __restrict__ zbuf, int N) {
    int t = threadIdx.x;
    int wave = t >> 6, lane = t & 63;
    int sub = lane >> 4, li = lane & 15;
    int node = (blockIdx.x * 4 + wave) * 4 + sub;
    bool valid = node < N;
    float acc = 0.f;
    if (valid) {
        acc = xp[(size_t)node * 16 + li];
        int beg = row_start[node], end = row_start[node + 1];
        int j = beg;
        for (; j + 3 < end; j += 4) {
            int v0 = col[j], v1 = col[j + 1], v2 = col[j + 2], v3 = col[j + 3];
            float x0 = xp[(size_t)v0 * 16 + li];
            float x1 = xp[(size_t)v1 * 16 + li];
            float x2 = xp[(size_t)v2 * 16 + li];
            float x3 = xp[(size_t)v3 * 16 + li];
            acc += (x0 + x1) + (x2 + x3);
        }
        for (; j < end; ++j) acc += xp[(size_t)col[j] * 16 + li];
    }
    float y[8];
    {
        f32x4 b0 = ((const f32x4*)b1)[li * 2], b1v = ((const f32x4*)b1)[li * 2 + 1];
#pragma unroll
        for (int u = 0; u < 4; ++u) { y[u] = b0[u]; y[4 + u] = b1v[u]; }
    }
#pragma unroll
    for (int k = 0; k < F; ++k) {
        float zk = __shfl(acc, (lane & 48) | k, 64);
        f32x4 w0 = ((const f32x4*)(w1 + k * H))[li * 2];
        f32x4 w1v = ((const f32x4*)(w1 + k * H))[li * 2 + 1];
#pragma unroll
        for (int u = 0; u < 4; ++u) { y[u] += zk * w0[u]; y[4 + u] += zk * w1v[u]; }
    }
    if (valid) {
        f16x8 hz;
#pragma unroll
        for (int u = 0; u < 8; ++u) hz[u] = (_Float16)fmaxf(y[u], 0.f);
        ((f16x8*)zbuf)[(size_t)node * 16 + li] = hz;
    }
}

// ---------------- activate: y = relu(bn(y)) IN-PLACE, once per node (N*H work) ----------------
// raw ybuf is dead after mlp's stats; layers 1..4 gather only needs activated values.
__global__ __launch_bounds__(256) void activate_kernel(
    _Float16* __restrict__ y, const float* __restrict__ scale,
    const float* __restrict__ shift, int n8) {
    int i = blockIdx.x * blockDim.x + threadIdx.x;
    if (i >= n8) return;
    int c8 = (i & 15) * 8;
    f16x8 h = ((const f16x8*)y)[i];
    f32x4 s0 = *(const f32x4*)(scale + c8), s1 = *(const f32x4*)(scale + c8 + 4);
    f32x4 t0 = *(const f32x4*)(shift + c8), t1 = *(const f32x4*)(shift + c8 + 4);
    f16x8 o;
#pragma unroll
    for (int u = 0; u < 4; ++u) {
        o[u]     = (_Float16)fmaxf((float)h[u]     * s0[u] + t0[u], 0.f);
        o[4 + u] = (_Float16)fmaxf((float)h[4 + u] * s1[u] + t1[u], 0.f);
    }
    ((f16x8*)y)[i] = o;
}

// ---------------- layers 1..4: PURE packed-f16 gather-sum (BN pre-applied) ----------------
// 16 lanes per node (f16x8 = 16B slice each), 4 nodes per wave, 8-deep unroll.
__global__ __launch_bounds__(256) void gather_kernel(
    const _Float16* __restrict__ y, const int* __restrict__ row_start,
    const int* __restrict__ col, _Float16* __restrict__ zbuf, int N) {
    int t = threadIdx.x;
    int wave = t >> 6, lane = t & 63;
    int sub = lane >> 4, li = lane & 15;
    int node = (blockIdx.x * 4 + wave) * 4 + sub;
    if (node >= N) return;
    const f16x8* yp = (const f16x8*)y;
    f16x8 a = yp[(size_t)node * 16 + li];   // self term (already activated)
    int beg = row_start[node], end = row_start[node + 1];
    int j = beg;
    for (; j + 7 < end; j += 8) {
        int v0 = col[j], v1 = col[j + 1], v2 = col[j + 2], v3 = col[j + 3];
        int v4 = col[j + 4], v5 = col[j + 5], v6 = col[j + 6], v7 = col[j + 7];
        f16x8 h0 = yp[(size_t)v0 * 16 + li];
        f16x8 h1 = yp[(size_t)v1 * 16 + li];
        f16x8 h2 = yp[(size_t)v2 * 16 + li];
        f16x8 h3 = yp[(size_t)v3 * 16 + li];
        f16x8 h4 = yp[(size_t)v4 * 16 + li];
        f16x8 h5 = yp[(size_t)v5 * 16 + li];
        f16x8 h6 = yp[(size_t)v6 * 16 + li];
        f16x8 h7 = yp[(size_t)v7 * 16 + li];
        f16x8 s01 = h0 + h1, s23 = h2 + h3, s45 = h4 + h5, s67 = h6 + h7;
        a += (s01 + s23) + (s45 + s67);    // v_pk_add_f16 trees
    }
    for (; j + 3 < end; j += 4) {
        int v0 = col[j], v1 = col[j + 1], v2 = col[j + 2], v3 = col[j + 3];
        f16x8 h0 = yp[(size_t)v0 * 16 + li];
        f16x8 h1 = yp[(size_t)v1 * 16 + li];
        f16x8 h2 = yp[(size_t)v2 * 16 + li];
        f16x8 h3 = yp[(size_t)v3 * 16 + li];
        a += (h0 + h1) + (h2 + h3);
    }
    for (; j < end; ++j) a += yp[(size_t)col[j] * 16 + li];
    ((f16x8*)zbuf)[(size_t)node * 16 + li] = a;
}

// ---------------- fused MLP (MFMA f16, weights in LDS) + BN partials ----------------
template <bool FULL>
__global__ __launch_bounds__(512) void mlp_kernel(
    const _Float16* __restrict__ zbuf, const _Float16* __restrict__ w1f,
    const float* __restrict__ b1, const _Float16* __restrict__ w2f,
    const float* __restrict__ b2, _Float16* __restrict__ ybuf,
    float* __restrict__ partials, int N, int nST) {
    __shared__ _Float16 lds[FULL ? (32768 + 8 * 16 * 136) : 16384];
    __shared__ float red[8 * 256];
    const int t = threadIdx.x;
    const int wave = t >> 6, lane = t & 63;
    const int li = lane & 15, kg = lane >> 4;

    _Float16* wl1 = lds;
    _Float16* wl2 = FULL ? (lds + 16384) : lds;

    if constexpr (FULL) {
        const f16x8* s1 = (const f16x8*)w1f;
        const f16x8* s2 = (const f16x8*)w2f;
        f16x8* d1 = (f16x8*)wl1;
        f16x8* d2 = (f16x8*)wl2;
        for (int i = t; i < 2048; i += 512) { d1[i] = s1[i]; d2[i] = s2[i]; }
    } else {
        const f16x8* s2 = (const f16x8*)w2f;
        f16x8* d2 = (f16x8*)wl2;
        for (int i = t; i < 2048; i += 512) d2[i] = s2[i];
    }
    __syncthreads();

    float ss1[8], ss2[8];
#pragma unroll
    for (int tt = 0; tt < 8; ++tt) { ss1[tt] = 0.f; ss2[tt] = 0.f; }

    const f32x4 z4 = {0.f, 0.f, 0.f, 0.f};
    const f16x8* wf1 = (const f16x8*)wl1;
    const f16x8* wf2 = (const f16x8*)wl2;

    for (int st = blockIdx.x; st < nST; st += gridDim.x) {
        const int node0 = st * 128 + wave * 16;
        f32x4 acc2[8];

        if constexpr (FULL) {
            _Float16* y1 = lds + 32768 + wave * (16 * 136);
            f32x4 acc1[8];
#pragma unroll
            for (int tt = 0; tt < 8; ++tt) acc1[tt] = z4;
            f16x8 a[4];
#pragma unroll
            for (int ks = 0; ks < 4; ++ks)
                a[ks] = *(const f16x8*)(zbuf + (size_t)(node0 + li) * H + ks * 32 + kg * 8);
#pragma unroll
            for (int ks = 0; ks < 4; ++ks)
#pragma unroll
                for (int tt = 0; tt < 8; ++tt)
                    acc1[tt] = __builtin_amdgcn_mfma_f32_16x16x32_f16(
                        a[ks], wf1[(tt * 4 + ks) * 64 + lane], acc1[tt], 0, 0, 0);
#pragma unroll
            for (int tt = 0; tt < 8; ++tt) {
                int c = tt * 16 + li;
                float bb = b1[c];
#pragma unroll
                for (int r = 0; r < 4; ++r)
                    y1[(kg * 4 + r) * 136 + c] = (_Float16)fmaxf(acc1[tt][r] + bb, 0.f);
            }
#pragma unroll
            for (int tt = 0; tt < 8; ++tt) acc2[tt] = z4;
            f16x8 a2[4];
#pragma unroll
            for (int ks = 0; ks < 4; ++ks)
                a2[ks] = *(const f16x8*)(y1 + li * 136 + ks * 32 + kg * 8);
#pragma unroll
            for (int ks = 0; ks < 4; ++ks)
#pragma unroll
                for (int tt = 0; tt < 8; ++tt)
                    acc2[tt] = __builtin_amdgcn_mfma_f32_16x16x32_f16(
                        a2[ks], wf2[(tt * 4 + ks) * 64 + lane], acc2[tt], 0, 0, 0);
        } else {
#pragma unroll
            for (int tt = 0; tt < 8; ++tt) acc2[tt] = z4;
            f16x8 a[4];
#pragma unroll
            for (int ks = 0; ks < 4; ++ks)
                a[ks] = *(const f16x8*)(zbuf + (size_t)(node0 + li) * H + ks * 32 + kg * 8);
#pragma unroll
            for (int ks = 0; ks < 4; ++ks)
#pragma unroll
                for (int tt = 0; tt < 8; ++tt)
                    acc2[tt] = __builtin_amdgcn_mfma_f32_16x16x32_f16(
                        a[ks], wf2[(tt * 4 + ks) * 64 + lane], acc2[tt], 0, 0, 0);
        }

#pragma unroll
        for (int tt = 0; tt < 8; ++tt) {
            int c = tt * 16 + li;
            float bb = b2[c];
#pragma unroll
            for (int r = 0; r < 4; ++r) {
                int node = node0 + kg * 4 + r;
                float v = acc2[tt][r] + bb;
                if (node < N) {
                    ybuf[(size_t)node * H + c] = (_Float16)v;
                    ss1[tt] += v; ss2[tt] += v * v;
                }
            }
        }
    }

    // block-level stats reduce: wave shfl -> LDS -> one plain store per slot
#pragma unroll
    for (int tt = 0; tt < 8; ++tt) {
        float s1 = ss1[tt], s2 = ss2[tt];
        s1 += __shfl_xor(s1, 16, 64); s2 += __shfl_xor(s2, 16, 64);
        s1 += __shfl_xor(s1, 32, 64); s2 += __shfl_xor(s2, 32, 64);
        if (kg == 0) {
            red[wave * 256 + tt * 16 + li] = s1;
            red[wave * 256 + 128 + tt * 16 + li] = s2;
        }
    }
    __syncthreads();
    if (t < 256) {
        float s = 0.f;
#pragma unroll
        for (int w = 0; w < 8; ++w) s += red[w * 256 + t];
        partials[(size_t)blockIdx.x * 256 + t] = s;
    }
}

// reduce partials[MLPB][256] -> scale/shift
__global__ void stats_final_kernel(const float* __restrict__ partials,
                                   const float* __restrict__ gamma,
                                   const float* __restrict__ beta, float* __restrict__ scale,
                                   float* __restrict__ shift, int N) {
    __shared__ float sdata[256];
    int t = threadIdx.x;   // 256 threads
    float s = 0.f;
    for (int b = 0; b < MLPB; ++b) s += partials[b * 256 + t];
    sdata[t] = s;
    __syncthreads();
    if (t < 128) {
        float invN = 1.f / (float)N;
        float mean = sdata[t] * invN;
        float var = sdata[128 + t] * invN - mean * mean;
        float inv = rsqrtf(var + BN_EPS);
        float sc = gamma[t] * inv;
        scale[t] = sc;
        shift[t] = beta[t] - mean * sc;
    }
}

__global__ void finalize_kernel(const _Float16* __restrict__ ybuf, const float* __restrict__ scale,
                                const float* __restrict__ shift, const int* __restrict__ batch,
                                float* __restrict__ out, int N) {
    int nh4 = N * (H / 4);
    int total = nh4 + N;
    for (int i = blockIdx.x * blockDim.x + threadIdx.x; i < total; i += gridDim.x * blockDim.x) {
        if (i < nh4) {
            f16x4 h = ((const f16x4*)ybuf)[i];
            int c = (i & 31) * 4;
            f32x4 sc = *(const f32x4*)(scale + c);
            f32x4 sh = *(const f32x4*)(shift + c);
            f32x4 o;
#pragma unroll
            for (int u = 0; u < 4; ++u) o[u] = fmaxf((float)h[u] * sc[u] + sh[u], 0.f);
            ((f32x4*)out)[i] = o;
        } else {
            int b = i - nh4;
            out[(size_t)N * H + b] = (float)batch[b];
        }
    }
}

// ---------------- launch ----------------

extern "C" void kernel_launch(void* const* d_in, const int* in_sizes, int n_in,
                              void* d_out, int out_size, void* d_ws, size_t ws_size,
                              hipStream_t stream) {
    const float* x      = (const float*)d_in[0];
    const int*   eidx   = (const int*)d_in[1];
    const int*   batch  = (const int*)d_in[2];
    const float* w1_0   = (const float*)d_in[3];
    const float* b1_0   = (const float*)d_in[4];
    const float* w2_0   = (const float*)d_in[5];
    const float* b2_0   = (const float*)d_in[6];
    const float* gamma0 = (const float*)d_in[7];
    const float* beta0  = (const float*)d_in[8];
    const float* ws1    = (const float*)d_in[9];
    const float* bs1    = (const float*)d_in[10];
    const float* ws2    = (const float*)d_in[11];
    const float* bs2    = (const float*)d_in[12];
    const float* gammas = (const float*)d_in[13];
    const float* betas  = (const float*)d_in[14];

    const int N = in_sizes[2];
    const int E = in_sizes[1] / 2;
    const int Npad2 = (N + 127) & ~127;   // supertile-aligned
    const int* srcv = eidx;          // edge_index[0]
    const int* dstv = eidx + E;      // edge_index[1]

    char* p = (char*)d_ws;
    size_t o = 0;
    auto alloc = [&](size_t bytes) {
        void* r = p + o;
        o = (o + bytes + 255) & ~(size_t)255;
        return r;
    };
    int* col        = (int*)alloc((size_t)E * 4);
    int* row_start  = (int*)alloc((size_t)(N + 1) * 4);
    int* bcnt       = (int*)alloc(NBMAX * 4);
    int* bbase      = (int*)alloc(NBMAX * 4);
    int* bcur       = (int*)alloc(NBMAX * 4);
    _Float16* wt    = (_Float16*)alloc((size_t)9 * 16384 * 2);
    float* partials = (float*)alloc((size_t)MLPB * 256 * 4);
    float* scale    = (float*)alloc(128 * 4);
    float* shift    = (float*)alloc(128 * 4);
    float* xp       = (float*)alloc((size_t)N * 16 * 4);
    _Float16* zbuf  = (_Float16*)alloc((size_t)Npad2 * H * 2);
    _Float16* ybuf  = (_Float16*)alloc((size_t)Npad2 * H * 2);
    int* ebuf       = (int*)zbuf;   // alias: ebuf (E*4B) dead before zbuf first written
    (void)ws_size; (void)n_in; (void)out_size;

    const int nbuckets = (N + 255) >> 8;
    const int nST = Npad2 / 128;         // 128-node supertiles
    const int gblocks = (N + 15) / 16;   // 16 nodes per block
    const int fchunk = (E + 255) / 256;  // edges per bucket_fill block
    const int n8 = N * 16;               // f16x8 chunks in ybuf

    // bucketed CSR build
    hipMemsetAsync(bcnt, 0, NBMAX * 4, stream);
    bucket_count_kernel<<<256, 256, 0, stream>>>(dstv, bcnt, E, nbuckets);
    bucket_scan_kernel<<<1, NBMAX, 0, stream>>>(bcnt, bbase, bcur, nbuckets);
    bucket_fill_kernel<<<256, 256, 0, stream>>>(srcv, dstv, bcur, ebuf, E, nbuckets, fchunk);
    csr_build_kernel<<<nbuckets, 256, 0, stream>>>(bbase, bcnt, ebuf, row_start, col, N, E);

    prep_w_kernel<<<(9 * 16384 + 255) / 256, 256, 0, stream>>>(w2_0, ws1, ws2, wt);
    prep_x_kernel<<<(N * 16 + 255) / 256, 256, 0, stream>>>(x, xp, N);

    // layer 0: gather over xp with fused 9->128 linear; then half-MLP + stats
    gather0_kernel<<<gblocks, 256, 0, stream>>>(xp, row_start, col, w1_0, b1_0, zbuf, N);
    mlp_kernel<false><<<MLPB, 512, 0, stream>>>(zbuf, nullptr, nullptr, wt, b2_0, ybuf, partials, N, nST);
    stats_final_kernel<<<1, 256, 0, stream>>>(partials, gamma0, beta0, scale, shift, N);

    // layers 1..4: activate(in-place) -> pure-sum gather -> mlp -> stats
    for (int l = 1; l <= 4; ++l) {
        activate_kernel<<<(n8 + 255) / 256, 256, 0, stream>>>(ybuf, scale, shift, n8);
        gather_kernel<<<gblocks, 256, 0, stream>>>(ybuf, row_start, col, zbuf, N);
        mlp_kernel<true><<<MLPB, 512, 0, stream>>>(
            zbuf, wt + (size_t)(4 + l) * 16384, bs1 + (size_t)(l - 1) * H,
            wt + (size_t)l * 16384, bs2 + (size_t)(l - 1) * H, ybuf, partials, N, nST);
        stats_final_kernel<<<1, 256, 0, stream>>>(partials, gammas + (size_t)(l - 1) * H,
                                                  betas + (size_t)(l - 1) * H, scale, shift, N);
    }

    finalize_kernel<<<2048, 256, 0, stream>>>(ybuf, scale, shift, batch, (float*)d_out, N);
}

// Round 9
// 516.807 us; speedup vs baseline: 1.2037x; 1.2037x over previous
//
#include <hip/hip_runtime.h>

constexpr int H = 128;
constexpr int F = 9;
constexpr float BN_EPS = 1e-5f;
constexpr int NBMAX = 512;      // max dst buckets (256 nodes each, N <= 131072)
constexpr int MLPB = 256;       // mlp grid size (fixed: partials slots)

typedef _Float16 f16x8 __attribute__((ext_vector_type(8)));
typedef _Float16 f16x4 __attribute__((ext_vector_type(4)));
typedef float    f32x4 __attribute__((ext_vector_type(4)));
typedef float    f32x2 __attribute__((ext_vector_type(2)));

// ---------------- bucketed CSR build (no per-node global atomics) ----------------

__global__ __launch_bounds__(256) void bucket_count_kernel(
    const int* __restrict__ dst, int* __restrict__ bcnt, int E, int nbuckets) {
    __shared__ int h[NBMAX];
    int t = threadIdx.x;
    for (int i = t; i < nbuckets; i += 256) h[i] = 0;
    __syncthreads();
    for (int i = blockIdx.x * 256 + t; i < E; i += gridDim.x * 256)
        atomicAdd(&h[dst[i] >> 8], 1);
    __syncthreads();
    for (int i = t; i < nbuckets; i += 256) {
        int c = h[i];
        if (c) atomicAdd(&bcnt[i], c);
    }
}

__global__ __launch_bounds__(NBMAX) void bucket_scan_kernel(
    const int* __restrict__ bcnt, int* __restrict__ bbase, int* __restrict__ bcur, int nbuckets) {
    __shared__ int s[NBMAX];
    int t = threadIdx.x;
    int v = (t < nbuckets) ? bcnt[t] : 0;
    s[t] = v;
    __syncthreads();
    for (int off = 1; off < NBMAX; off <<= 1) {
        int tmp = (t >= off) ? s[t - off] : 0;
        __syncthreads();
        s[t] += tmp;
        __syncthreads();
    }
    if (t < nbuckets) {
        int ex = s[t] - v;
        bbase[t] = ex;
        bcur[t] = ex;
    }
}

// Pass B: group edges by bucket; packed entry = src | ((dst&255)<<17)  (src < 2^17)
__global__ __launch_bounds__(256) void bucket_fill_kernel(
    const int* __restrict__ src, const int* __restrict__ dst, int* __restrict__ bcur,
    int* __restrict__ ebuf, int E, int nbuckets, int chunk) {
    __shared__ int h[NBMAX];
    int t = threadIdx.x;
    for (int i = t; i < nbuckets; i += 256) h[i] = 0;
    __syncthreads();
    int lo = blockIdx.x * chunk, hi = min(E, lo + chunk);
    for (int i = lo + t; i < hi; i += 256)
        atomicAdd(&h[dst[i] >> 8], 1);
    __syncthreads();
    for (int i = t; i < nbuckets; i += 256) {
        int c = h[i];
        h[i] = c ? atomicAdd(&bcur[i], c) : 0;   // h becomes block's write cursor
    }
    __syncthreads();
    for (int i = lo + t; i < hi; i += 256) {
        int d = dst[i];
        int p = atomicAdd(&h[d >> 8], 1);        // LDS atomic
        ebuf[p] = src[i] | ((d & 255) << 17);
    }
}

__global__ __launch_bounds__(256) void csr_build_kernel(
    const int* __restrict__ bbase, const int* __restrict__ bcnt,
    const int* __restrict__ ebuf, int* __restrict__ row_start,
    int* __restrict__ col, int N, int E) {
    __shared__ int hist[256];
    __shared__ int sc[256];
    int b = blockIdx.x, t = threadIdx.x;
    int beg = bbase[b], cnt = bcnt[b];
    hist[t] = 0;
    __syncthreads();
    for (int i = t; i < cnt; i += 256)
        atomicAdd(&hist[(ebuf[beg + i] >> 17) & 255], 1);
    __syncthreads();
    int v = hist[t];
    sc[t] = v;
    __syncthreads();
    for (int off = 1; off < 256; off <<= 1) {
        int tmp = (t >= off) ? sc[t - off] : 0;
        __syncthreads();
        sc[t] += tmp;
        __syncthreads();
    }
    int ex = sc[t] - v;                 // exclusive prefix within bucket
    int node = b * 256 + t;
    if (node < N) row_start[node] = beg + ex;
    hist[t] = ex;                       // becomes per-node cursor
    __syncthreads();
    for (int i = t; i < cnt; i += 256) {
        int e = ebuf[beg + i];
        int p = atomicAdd(&hist[(e >> 17) & 255], 1);   // LDS atomic
        col[beg + p] = e & 0x1FFFF;
    }
    if (b == 0 && t == 0) row_start[N] = E;
}

// ---------------- weight prep: f32 (K x 128) -> f16 in MFMA-FRAGMENT order ----------------
// slot 0: w2_0 ; slots 1..4: ws2[0..3] ; slots 5..8: ws1[0..3]
__global__ void prep_w_kernel(const float* __restrict__ w20, const float* __restrict__ ws1,
                              const float* __restrict__ ws2, _Float16* __restrict__ wf) {
    int i = blockIdx.x * blockDim.x + threadIdx.x;
    if (i >= 9 * 16384) return;
    int w = i >> 14, r = i & 16383;
    int tt = r >> 11, ks = (r >> 9) & 3, lane = (r >> 3) & 63, e = r & 7;
    int n = tt * 16 + (lane & 15);
    int k = ks * 32 + (lane >> 4) * 8 + e;
    const float* src = (w == 0) ? w20 : (w <= 4 ? ws2 + (size_t)(w - 1) * 16384
                                                : ws1 + (size_t)(w - 5) * 16384);
    wf[i] = (_Float16)src[k * H + n];
}

// pad x (N x 9 f32) -> xp (N x 16 f32, zero-padded)
__global__ void prep_x_kernel(const float* __restrict__ x, float* __restrict__ xp, int N) {
    int i = blockIdx.x * blockDim.x + threadIdx.x;
    if (i >= N * 16) return;
    int n = i >> 4, c = i & 15;
    xp[i] = (c < F) ? x[n * F + c] : 0.f;
}

// ---------------- layer 0: gather (padded F=16) + fused 9->128 linear + ReLU ----------------
__global__ __launch_bounds__(256) void gather0_kernel(
    const float* __restrict__ xp, const int* __restrict__ row_start,
    const int* __restrict__ col, const float* __restrict__ w1,
    const float* __restrict__ b1, _Float16* __restrict__ zbuf, int N) {
    int t = threadIdx.x;
    int wave = t >> 6, lane = t & 63;
    int sub = lane >> 4, li = lane & 15;
    int node = (blockIdx.x * 4 + wave) * 4 + sub;
    bool valid = node < N;
    float acc = 0.f;
    if (valid) {
        acc = xp[(size_t)node * 16 + li];
        int beg = row_start[node], end = row_start[node + 1];
        int j = beg;
        for (; j + 3 < end; j += 4) {
            int v0 = col[j], v1 = col[j + 1], v2 = col[j + 2], v3 = col[j + 3];
            float x0 = xp[(size_t)v0 * 16 + li];
            float x1 = xp[(size_t)v1 * 16 + li];
            float x2 = xp[(size_t)v2 * 16 + li];
            float x3 = xp[(size_t)v3 * 16 + li];
            acc += (x0 + x1) + (x2 + x3);
        }
        for (; j < end; ++j) acc += xp[(size_t)col[j] * 16 + li];
    }
    float y[8];
    {
        f32x4 b0 = ((const f32x4*)b1)[li * 2], b1v = ((const f32x4*)b1)[li * 2 + 1];
#pragma unroll
        for (int u = 0; u < 4; ++u) { y[u] = b0[u]; y[4 + u] = b1v[u]; }
    }
#pragma unroll
    for (int k = 0; k < F; ++k) {
        float zk = __shfl(acc, (lane & 48) | k, 64);
        f32x4 w0 = ((const f32x4*)(w1 + k * H))[li * 2];
        f32x4 w1v = ((const f32x4*)(w1 + k * H))[li * 2 + 1];
#pragma unroll
        for (int u = 0; u < 4; ++u) { y[u] += zk * w0[u]; y[4 + u] += zk * w1v[u]; }
    }
    if (valid) {
        f16x8 hz;
#pragma unroll
        for (int u = 0; u < 8; ++u) hz[u] = (_Float16)fmaxf(y[u], 0.f);
        ((f16x8*)zbuf)[(size_t)node * 16 + li] = hz;
    }
}

// ---------------- convert: abuf(fp8) = relu(bn(ybuf)), once per node (N*H) ----------------
__global__ __launch_bounds__(256) void convert_kernel(
    const _Float16* __restrict__ y, const float* __restrict__ scale,
    const float* __restrict__ shift, uint2* __restrict__ a8, int n8) {
    int i = blockIdx.x * blockDim.x + threadIdx.x;
    if (i >= n8) return;
    int c8 = (i & 15) * 8;
    f16x8 h = ((const f16x8*)y)[i];
    f32x4 s0 = *(const f32x4*)(scale + c8), s1 = *(const f32x4*)(scale + c8 + 4);
    f32x4 t0 = *(const f32x4*)(shift + c8), t1 = *(const f32x4*)(shift + c8 + 4);
    float v[8];
#pragma unroll
    for (int u = 0; u < 4; ++u) {
        v[u]     = fmaxf((float)h[u]     * s0[u] + t0[u], 0.f);
        v[4 + u] = fmaxf((float)h[4 + u] * s1[u] + t1[u], 0.f);
    }
    unsigned int lo = 0, hi = 0;
    lo = __builtin_amdgcn_cvt_pk_fp8_f32(v[0], v[1], lo, false);  // bytes 0-1
    lo = __builtin_amdgcn_cvt_pk_fp8_f32(v[2], v[3], lo, true);   // bytes 2-3
    hi = __builtin_amdgcn_cvt_pk_fp8_f32(v[4], v[5], hi, false);
    hi = __builtin_amdgcn_cvt_pk_fp8_f32(v[6], v[7], hi, true);
    a8[i] = make_uint2(lo, hi);
}

__device__ inline void acc_fp8(float* a, uint2 r) {
    f32x2 p0 = __builtin_amdgcn_cvt_pk_f32_fp8(r.x, false);
    f32x2 p1 = __builtin_amdgcn_cvt_pk_f32_fp8(r.x, true);
    f32x2 p2 = __builtin_amdgcn_cvt_pk_f32_fp8(r.y, false);
    f32x2 p3 = __builtin_amdgcn_cvt_pk_f32_fp8(r.y, true);
    a[0] += p0.x; a[1] += p0.y; a[2] += p1.x; a[3] += p1.y;
    a[4] += p2.x; a[5] += p2.y; a[6] += p3.x; a[7] += p3.y;
}

// ---------------- layers 1..4: fp8 gather-sum (half the bytes of f16) ----------------
// 16 lanes per node (uint2 = 8B = 8 fp8 each), 4 nodes per wave, 8-deep unroll.
__global__ __launch_bounds__(256) void gather_kernel(
    const uint2* __restrict__ a8, const int* __restrict__ row_start,
    const int* __restrict__ col, _Float16* __restrict__ zbuf, int N) {
    int t = threadIdx.x;
    int wave = t >> 6, lane = t & 63;
    int sub = lane >> 4, li = lane & 15;
    int node = (blockIdx.x * 4 + wave) * 4 + sub;
    if (node >= N) return;
    float a[8] = {0.f, 0.f, 0.f, 0.f, 0.f, 0.f, 0.f, 0.f};
    acc_fp8(a, a8[(size_t)node * 16 + li]);   // self term (activated)
    int beg = row_start[node], end = row_start[node + 1];
    int j = beg;
    for (; j + 7 < end; j += 8) {
        int v0 = col[j], v1 = col[j + 1], v2 = col[j + 2], v3 = col[j + 3];
        int v4 = col[j + 4], v5 = col[j + 5], v6 = col[j + 6], v7 = col[j + 7];
        uint2 h0 = a8[(size_t)v0 * 16 + li];
        uint2 h1 = a8[(size_t)v1 * 16 + li];
        uint2 h2 = a8[(size_t)v2 * 16 + li];
        uint2 h3 = a8[(size_t)v3 * 16 + li];
        uint2 h4 = a8[(size_t)v4 * 16 + li];
        uint2 h5 = a8[(size_t)v5 * 16 + li];
        uint2 h6 = a8[(size_t)v6 * 16 + li];
        uint2 h7 = a8[(size_t)v7 * 16 + li];
        acc_fp8(a, h0); acc_fp8(a, h1); acc_fp8(a, h2); acc_fp8(a, h3);
        acc_fp8(a, h4); acc_fp8(a, h5); acc_fp8(a, h6); acc_fp8(a, h7);
    }
    for (; j + 3 < end; j += 4) {
        int v0 = col[j], v1 = col[j + 1], v2 = col[j + 2], v3 = col[j + 3];
        uint2 h0 = a8[(size_t)v0 * 16 + li];
        uint2 h1 = a8[(size_t)v1 * 16 + li];
        uint2 h2 = a8[(size_t)v2 * 16 + li];
        uint2 h3 = a8[(size_t)v3 * 16 + li];
        acc_fp8(a, h0); acc_fp8(a, h1); acc_fp8(a, h2); acc_fp8(a, h3);
    }
    for (; j < end; ++j) acc_fp8(a, a8[(size_t)col[j] * 16 + li]);
    f16x8 hz;
#pragma unroll
    for (int u = 0; u < 8; ++u) hz[u] = (_Float16)a[u];
    ((f16x8*)zbuf)[(size_t)node * 16 + li] = hz;
}

// ---------------- fused MLP (MFMA f16, weights in LDS) + BN partials ----------------
template <bool FULL>
__global__ __launch_bounds__(512) void mlp_kernel(
    const _Float16* __restrict__ zbuf, const _Float16* __restrict__ w1f,
    const float* __restrict__ b1, const _Float16* __restrict__ w2f,
    const float* __restrict__ b2, _Float16* __restrict__ ybuf,
    float* __restrict__ partials, int N, int nST) {
    __shared__ _Float16 lds[FULL ? (32768 + 8 * 16 * 136) : 16384];
    __shared__ float red[8 * 256];
    const int t = threadIdx.x;
    const int wave = t >> 6, lane = t & 63;
    const int li = lane & 15, kg = lane >> 4;

    _Float16* wl1 = lds;
    _Float16* wl2 = FULL ? (lds + 16384) : lds;

    if constexpr (FULL) {
        const f16x8* s1 = (const f16x8*)w1f;
        const f16x8* s2 = (const f16x8*)w2f;
        f16x8* d1 = (f16x8*)wl1;
        f16x8* d2 = (f16x8*)wl2;
        for (int i = t; i < 2048; i += 512) { d1[i] = s1[i]; d2[i] = s2[i]; }
    } else {
        const f16x8* s2 = (const f16x8*)w2f;
        f16x8* d2 = (f16x8*)wl2;
        for (int i = t; i < 2048; i += 512) d2[i] = s2[i];
    }
    __syncthreads();

    float ss1[8], ss2[8];
#pragma unroll
    for (int tt = 0; tt < 8; ++tt) { ss1[tt] = 0.f; ss2[tt] = 0.f; }

    const f32x4 z4 = {0.f, 0.f, 0.f, 0.f};
    const f16x8* wf1 = (const f16x8*)wl1;
    const f16x8* wf2 = (const f16x8*)wl2;

    for (int st = blockIdx.x; st < nST; st += gridDim.x) {
        const int node0 = st * 128 + wave * 16;
        f32x4 acc2[8];

        if constexpr (FULL) {
            _Float16* y1 = lds + 32768 + wave * (16 * 136);
            f32x4 acc1[8];
#pragma unroll
            for (int tt = 0; tt < 8; ++tt) acc1[tt] = z4;
            f16x8 a[4];
#pragma unroll
            for (int ks = 0; ks < 4; ++ks)
                a[ks] = *(const f16x8*)(zbuf + (size_t)(node0 + li) * H + ks * 32 + kg * 8);
#pragma unroll
            for (int ks = 0; ks < 4; ++ks)
#pragma unroll
                for (int tt = 0; tt < 8; ++tt)
                    acc1[tt] = __builtin_amdgcn_mfma_f32_16x16x32_f16(
                        a[ks], wf1[(tt * 4 + ks) * 64 + lane], acc1[tt], 0, 0, 0);
#pragma unroll
            for (int tt = 0; tt < 8; ++tt) {
                int c = tt * 16 + li;
                float bb = b1[c];
#pragma unroll
                for (int r = 0; r < 4; ++r)
                    y1[(kg * 4 + r) * 136 + c] = (_Float16)fmaxf(acc1[tt][r] + bb, 0.f);
            }
#pragma unroll
            for (int tt = 0; tt < 8; ++tt) acc2[tt] = z4;
            f16x8 a2[4];
#pragma unroll
            for (int ks = 0; ks < 4; ++ks)
                a2[ks] = *(const f16x8*)(y1 + li * 136 + ks * 32 + kg * 8);
#pragma unroll
            for (int ks = 0; ks < 4; ++ks)
#pragma unroll
                for (int tt = 0; tt < 8; ++tt)
                    acc2[tt] = __builtin_amdgcn_mfma_f32_16x16x32_f16(
                        a2[ks], wf2[(tt * 4 + ks) * 64 + lane], acc2[tt], 0, 0, 0);
        } else {
#pragma unroll
            for (int tt = 0; tt < 8; ++tt) acc2[tt] = z4;
            f16x8 a[4];
#pragma unroll
            for (int ks = 0; ks < 4; ++ks)
                a[ks] = *(const f16x8*)(zbuf + (size_t)(node0 + li) * H + ks * 32 + kg * 8);
#pragma unroll
            for (int ks = 0; ks < 4; ++ks)
#pragma unroll
                for (int tt = 0; tt < 8; ++tt)
                    acc2[tt] = __builtin_amdgcn_mfma_f32_16x16x32_f16(
                        a[ks], wf2[(tt * 4 + ks) * 64 + lane], acc2[tt], 0, 0, 0);
        }

#pragma unroll
        for (int tt = 0; tt < 8; ++tt) {
            int c = tt * 16 + li;
            float bb = b2[c];
#pragma unroll
            for (int r = 0; r < 4; ++r) {
                int node = node0 + kg * 4 + r;
                float v = acc2[tt][r] + bb;
                if (node < N) {
                    ybuf[(size_t)node * H + c] = (_Float16)v;
                    ss1[tt] += v; ss2[tt] += v * v;
                }
            }
        }
    }

    // block-level stats reduce: wave shfl -> LDS -> one plain store per slot
#pragma unroll
    for (int tt = 0; tt < 8; ++tt) {
        float s1 = ss1[tt], s2 = ss2[tt];
        s1 += __shfl_xor(s1, 16, 64); s2 += __shfl_xor(s2, 16, 64);
        s1 += __shfl_xor(s1, 32, 64); s2 += __shfl_xor(s2, 32, 64);
        if (kg == 0) {
            red[wave * 256 + tt * 16 + li] = s1;
            red[wave * 256 + 128 + tt * 16 + li] = s2;
        }
    }
    __syncthreads();
    if (t < 256) {
        float s = 0.f;
#pragma unroll
        for (int w = 0; w < 8; ++w) s += red[w * 256 + t];
        partials[(size_t)blockIdx.x * 256 + t] = s;
    }
}

// reduce partials[MLPB][256] -> scale/shift
__global__ void stats_final_kernel(const float* __restrict__ partials,
                                   const float* __restrict__ gamma,
                                   const float* __restrict__ beta, float* __restrict__ scale,
                                   float* __restrict__ shift, int N) {
    __shared__ float sdata[256];
    int t = threadIdx.x;   // 256 threads
    float s = 0.f;
    for (int b = 0; b < MLPB; ++b) s += partials[b * 256 + t];
    sdata[t] = s;
    __syncthreads();
    if (t < 128) {
        float invN = 1.f / (float)N;
        float mean = sdata[t] * invN;
        float var = sdata[128 + t] * invN - mean * mean;
        float inv = rsqrtf(var + BN_EPS);
        float sc = gamma[t] * inv;
        scale[t] = sc;
        shift[t] = beta[t] - mean * sc;
    }
}

__global__ void finalize_kernel(const _Float16* __restrict__ ybuf, const float* __restrict__ scale,
                                const float* __restrict__ shift, const int* __restrict__ batch,
                                float* __restrict__ out, int N) {
    int nh4 = N * (H / 4);
    int total = nh4 + N;
    for (int i = blockIdx.x * blockDim.x + threadIdx.x; i < total; i += gridDim.x * blockDim.x) {
        if (i < nh4) {
            f16x4 h = ((const f16x4*)ybuf)[i];
            int c = (i & 31) * 4;
            f32x4 sc = *(const f32x4*)(scale + c);
            f32x4 sh = *(const f32x4*)(shift + c);
            f32x4 o;
#pragma unroll
            for (int u = 0; u < 4; ++u) o[u] = fmaxf((float)h[u] * sc[u] + sh[u], 0.f);
            ((f32x4*)out)[i] = o;
        } else {
            int b = i - nh4;
            out[(size_t)N * H + b] = (float)batch[b];
        }
    }
}

// ---------------- launch ----------------

extern "C" void kernel_launch(void* const* d_in, const int* in_sizes, int n_in,
                              void* d_out, int out_size, void* d_ws, size_t ws_size,
                              hipStream_t stream) {
    const float* x      = (const float*)d_in[0];
    const int*   eidx   = (const int*)d_in[1];
    const int*   batch  = (const int*)d_in[2];
    const float* w1_0   = (const float*)d_in[3];
    const float* b1_0   = (const float*)d_in[4];
    const float* w2_0   = (const float*)d_in[5];
    const float* b2_0   = (const float*)d_in[6];
    const float* gamma0 = (const float*)d_in[7];
    const float* beta0  = (const float*)d_in[8];
    const float* ws1    = (const float*)d_in[9];
    const float* bs1    = (const float*)d_in[10];
    const float* ws2    = (const float*)d_in[11];
    const float* bs2    = (const float*)d_in[12];
    const float* gammas = (const float*)d_in[13];
    const float* betas  = (const float*)d_in[14];

    const int N = in_sizes[2];
    const int E = in_sizes[1] / 2;
    const int Npad2 = (N + 127) & ~127;   // supertile-aligned
    const int* srcv = eidx;          // edge_index[0]
    const int* dstv = eidx + E;      // edge_index[1]

    char* p = (char*)d_ws;
    size_t o = 0;
    auto alloc = [&](size_t bytes) {
        void* r = p + o;
        o = (o + bytes + 255) & ~(size_t)255;
        return r;
    };
    int* col        = (int*)alloc((size_t)E * 4);
    int* row_start  = (int*)alloc((size_t)(N + 1) * 4);
    int* bcnt       = (int*)alloc(NBMAX * 4);
    int* bbase      = (int*)alloc(NBMAX * 4);
    int* bcur       = (int*)alloc(NBMAX * 4);
    _Float16* wt    = (_Float16*)alloc((size_t)9 * 16384 * 2);
    float* partials = (float*)alloc((size_t)MLPB * 256 * 4);
    float* scale    = (float*)alloc(128 * 4);
    float* shift    = (float*)alloc(128 * 4);
    float* xp       = (float*)alloc((size_t)N * 16 * 4);
    uint2* abuf     = (uint2*)alloc((size_t)Npad2 * 16 * 8);   // fp8 N x 128
    _Float16* zbuf  = (_Float16*)alloc((size_t)Npad2 * H * 2);
    _Float16* ybuf  = (_Float16*)alloc((size_t)Npad2 * H * 2);
    int* ebuf       = (int*)zbuf;   // alias: ebuf (E*4B) dead before zbuf first written
    (void)ws_size; (void)n_in; (void)out_size;

    const int nbuckets = (N + 255) >> 8;
    const int nST = Npad2 / 128;         // 128-node supertiles
    const int gblocks = (N + 15) / 16;   // 16 nodes per block
    const int fchunk = (E + 255) / 256;  // edges per bucket_fill block
    const int n8 = N * 16;               // f16x8 / uint2 chunks per buffer

    // bucketed CSR build
    hipMemsetAsync(bcnt, 0, NBMAX * 4, stream);
    bucket_count_kernel<<<256, 256, 0, stream>>>(dstv, bcnt, E, nbuckets);
    bucket_scan_kernel<<<1, NBMAX, 0, stream>>>(bcnt, bbase, bcur, nbuckets);
    bucket_fill_kernel<<<256, 256, 0, stream>>>(srcv, dstv, bcur, ebuf, E, nbuckets, fchunk);
    csr_build_kernel<<<nbuckets, 256, 0, stream>>>(bbase, bcnt, ebuf, row_start, col, N, E);

    prep_w_kernel<<<(9 * 16384 + 255) / 256, 256, 0, stream>>>(w2_0, ws1, ws2, wt);
    prep_x_kernel<<<(N * 16 + 255) / 256, 256, 0, stream>>>(x, xp, N);

    // layer 0: gather over xp with fused 9->128 linear; then half-MLP + stats
    gather0_kernel<<<gblocks, 256, 0, stream>>>(xp, row_start, col, w1_0, b1_0, zbuf, N);
    mlp_kernel<false><<<MLPB, 512, 0, stream>>>(zbuf, nullptr, nullptr, wt, b2_0, ybuf, partials, N, nST);
    stats_final_kernel<<<1, 256, 0, stream>>>(partials, gamma0, beta0, scale, shift, N);

    // layers 1..4: convert(ybuf->fp8 abuf) -> fp8 gather -> mlp -> stats
    for (int l = 1; l <= 4; ++l) {
        convert_kernel<<<(n8 + 255) / 256, 256, 0, stream>>>(ybuf, scale, shift, abuf, n8);
        gather_kernel<<<gblocks, 256, 0, stream>>>(abuf, row_start, col, zbuf, N);
        mlp_kernel<true><<<MLPB, 512, 0, stream>>>(
            zbuf, wt + (size_t)(4 + l) * 16384, bs1 + (size_t)(l - 1) * H,
            wt + (size_t)l * 16384, bs2 + (size_t)(l - 1) * H, ybuf, partials, N, nST);
        stats_final_kernel<<<1, 256, 0, stream>>>(partials, gammas + (size_t)(l - 1) * H,
                                                  betas + (size_t)(l - 1) * H, scale, shift, N);
    }

    finalize_kernel<<<2048, 256, 0, stream>>>(ybuf, scale, shift, batch, (float*)d_out, N);
}